// Round 1
// baseline (3082.475 us; speedup 1.0000x reference)
//
#include <hip/hip_runtime.h>
#include <hip/hip_bf16.h>

#define FDIM 64
#define LFP 128
#define RROUNDS 4
#define NPB 128  // nodes per block in mlp kernel

__global__ void init_kernel(const int* __restrict__ feat, const float* __restrict__ table,
                            float* __restrict__ emb, float* __restrict__ f, int n) {
    int gid = blockIdx.x * blockDim.x + threadIdx.x;
    if (gid < n * FDIM) {
        int node = gid >> 6;
        int d = gid & 63;
        emb[gid] = table[feat[node] * FDIM + d];
    }
    if (gid < LFP) f[gid] = 0.f;
}

// one wave (64 lanes) per edge; lane = feature dim
__global__ void scatter_kernel(const float* __restrict__ emb, float* __restrict__ agg,
                               const int* __restrict__ src, const int* __restrict__ dst, int nE) {
    long long gid = (long long)blockIdx.x * blockDim.x + threadIdx.x;
    int e = (int)(gid >> 6);
    int d = (int)(gid & 63);
    if (e < nE) {
        int s = src[e];
        int t = dst[e];
        unsafeAtomicAdd(&agg[(long long)t * FDIM + d], emb[(long long)s * FDIM + d]);
    }
}

// thread-per-node MLP: v = emb+agg; r = relu(v@Wh+bh); logits = r@Wfp+bfp;
// softmax over 128; f += sum_n softmax; emb <- r (in place, block-local region only)
__global__ __launch_bounds__(NPB) void mlp_kernel(
        const float* __restrict__ emb, const float* __restrict__ agg, float* __restrict__ emb_out,
        const float* __restrict__ Wh, const float* __restrict__ bh,
        const float* __restrict__ Wfp, const float* __restrict__ bfp,
        float* __restrict__ f, int N) {
    __shared__ float vt[NPB * 65];  // padded: stride 65 kills bank conflicts
    int tid = threadIdx.x;
    int base = blockIdx.x * NPB;

    // cooperative coalesced load of the block's node tile: v = emb + agg
    for (int idx = tid; idx < NPB * FDIM; idx += NPB) {
        int nl = idx >> 6;
        int k = idx & 63;
        float val = 0.f;
        if (base + nl < N) {
            int g = base * FDIM + idx;
            val = emb[g] + agg[g];
        }
        vt[nl * 65 + k] = val;
    }
    __syncthreads();

    int n = base + tid;
    bool active = (n < N);

    // phase A: r = relu(v @ Wh + bh), r kept in registers
    float r[FDIM];
#pragma unroll
    for (int j = 0; j < FDIM; j++) r[j] = bh[j];
    for (int k = 0; k < FDIM; k++) {
        float vk = vt[tid * 65 + k];
#pragma unroll
        for (int j = 0; j < FDIM; j++) r[j] = fmaf(vk, Wh[k * FDIM + j], r[j]);
    }
#pragma unroll
    for (int j = 0; j < FDIM; j++) r[j] = fmaxf(r[j], 0.f);

    // write r into own LDS row (no sync needed: own row only), then coalesced store
#pragma unroll
    for (int j = 0; j < FDIM; j++) vt[tid * 65 + j] = r[j];
    __syncthreads();
    for (int idx = tid; idx < NPB * FDIM; idx += NPB) {
        int nl = idx >> 6;
        int k = idx & 63;
        if (base + nl < N) emb_out[base * FDIM + idx] = vt[nl * 65 + k];
    }

    // phase B pass 1: online softmax (max + sum) over 128 logits
    float m = -1e30f, s = 0.f;
    for (int l = 0; l < LFP; l++) {
        float acc = bfp[l];
#pragma unroll
        for (int j = 0; j < FDIM; j++) acc = fmaf(r[j], Wfp[j * LFP + l], acc);
        float mn = fmaxf(m, acc);
        s = s * __expf(m - mn) + __expf(acc - mn);
        m = mn;
    }
    float inv_s = active ? (1.f / s) : 0.f;

    // phase B pass 2: recompute logits, accumulate softmax into f via wave reduce
    for (int l = 0; l < LFP; l++) {
        float acc = bfp[l];
#pragma unroll
        for (int j = 0; j < FDIM; j++) acc = fmaf(r[j], Wfp[j * LFP + l], acc);
        float e = active ? __expf(acc - m) * inv_s : 0.f;
#pragma unroll
        for (int off = 32; off > 0; off >>= 1) e += __shfl_down(e, off);
        if ((tid & 63) == 0) unsafeAtomicAdd(&f[l], e);
    }
}

__global__ void final_kernel(const float* __restrict__ f, const float* __restrict__ Wcl,
                             const float* __restrict__ bcl, float* __restrict__ out) {
    __shared__ float logits[10];
    int c = threadIdx.x;
    if (c < 10) {
        float acc = bcl[c];
        for (int l = 0; l < LFP; l++) acc = fmaf(f[l], Wcl[l * 10 + c], acc);
        logits[c] = acc;
    }
    __syncthreads();
    if (c == 0) {
        float m = -1e30f;
        for (int i = 0; i < 10; i++) m = fmaxf(m, logits[i]);
        float e[10], s = 0.f;
        for (int i = 0; i < 10; i++) { e[i] = __expf(logits[i] - m); s += e[i]; }
        for (int i = 0; i < 10; i++) out[i] = e[i] / s;
    }
}

extern "C" void kernel_launch(void* const* d_in, const int* in_sizes, int n_in,
                              void* d_out, int out_size, void* d_ws, size_t ws_size,
                              hipStream_t stream) {
    const int* feat = (const int*)d_in[0];
    const int* esrc = (const int*)d_in[1];
    const int* edst = (const int*)d_in[2];
    const float* table = (const float*)d_in[3];
    const float* Wh = (const float*)d_in[4];
    const float* bh = (const float*)d_in[5];
    const float* Wfp = (const float*)d_in[6];
    const float* bfp = (const float*)d_in[7];
    const float* Wcl = (const float*)d_in[8];
    const float* bcl = (const float*)d_in[9];
    float* out = (float*)d_out;
    int N = in_sizes[0];
    int nE = in_sizes[1];

    float* emb = (float*)d_ws;
    float* agg = emb + (size_t)N * FDIM;
    float* f = agg + (size_t)N * FDIM;

    init_kernel<<<(N * FDIM + 255) / 256, 256, 0, stream>>>(feat, table, emb, f, N);

    for (int r = 0; r < RROUNDS; ++r) {
        hipMemsetAsync(agg, 0, (size_t)N * FDIM * sizeof(float), stream);
        long long tot = (long long)nE * FDIM;
        scatter_kernel<<<(int)((tot + 255) / 256), 256, 0, stream>>>(emb, agg, esrc, edst, nE);
        mlp_kernel<<<(N + NPB - 1) / NPB, NPB, 0, stream>>>(
            emb, agg, emb, Wh + (size_t)r * FDIM * FDIM, bh + (size_t)r * FDIM,
            Wfp + (size_t)r * FDIM * LFP, bfp + (size_t)r * LFP, f, N);
    }

    final_kernel<<<1, 64, 0, stream>>>(f, Wcl, bcl, out);
}

// Round 2
// 861.506 us; speedup vs baseline: 3.5780x; 3.5780x over previous
//
#include <hip/hip_runtime.h>
#include <hip/hip_bf16.h>

#define FDIM 64
#define LFP 128
#define RROUNDS 4
#define BM 64  // nodes per block in mlp kernel

typedef __attribute__((ext_vector_type(8))) short bf16x8;
typedef __attribute__((ext_vector_type(4))) float f32x4;

__device__ __forceinline__ float bf2f(unsigned short u) {
    unsigned int x = ((unsigned int)u) << 16;
    float f;
    __builtin_memcpy(&f, &x, 4);
    return f;
}
__device__ __forceinline__ unsigned short f2bf(float x) {
    unsigned int u;
    __builtin_memcpy(&u, &x, 4);
    unsigned int r = (u + 0x7fffu + ((u >> 16) & 1u)) >> 16;  // RNE
    return (unsigned short)r;
}

// convert weights to bf16, transposed: whT[r][j][k] = Wh[r][k][j]; wfpT[r][l][k] = Wfp[r][k][l]
__global__ void prep_kernel(const float* __restrict__ Wh, const float* __restrict__ Wfp,
                            unsigned short* __restrict__ whT, unsigned short* __restrict__ wfpT) {
    int o = blockIdx.x * blockDim.x + threadIdx.x;
    if (o < RROUNDS * FDIM * FDIM) {
        int r = o >> 12, rem = o & 4095, j = rem >> 6, k = rem & 63;
        whT[o] = f2bf(Wh[r * 4096 + k * 64 + j]);
    } else {
        int o2 = o - RROUNDS * FDIM * FDIM;
        int r = o2 >> 13, rem = o2 & 8191, l = rem >> 6, k = rem & 63;
        wfpT[o2] = f2bf(Wfp[r * 8192 + k * 128 + l]);
    }
}

__global__ void init_kernel(const int* __restrict__ feat, const float* __restrict__ table,
                            unsigned short* __restrict__ emb, float* __restrict__ f, int n) {
    int gid = blockIdx.x * blockDim.x + threadIdx.x;
    if (gid < n * FDIM) {
        int node = gid >> 6;
        int d = gid & 63;
        emb[gid] = f2bf(table[feat[node] * FDIM + d]);
    }
    if (gid < LFP) f[gid] = 0.f;
}

// one wave (64 lanes) per edge; lane = feature dim
__global__ void scatter_kernel(const unsigned short* __restrict__ emb, float* __restrict__ agg,
                               const int* __restrict__ src, const int* __restrict__ dst, int nE) {
    long long gid = (long long)blockIdx.x * blockDim.x + threadIdx.x;
    int e = (int)(gid >> 6);
    int d = (int)(gid & 63);
    if (e < nE) {
        int s = src[e];
        int t = dst[e];
        unsafeAtomicAdd(&agg[(long long)t * FDIM + d], bf2f(emb[(long long)s * FDIM + d]));
    }
}

// MFMA MLP: block = 64 nodes, 4 waves. LDS tiles padded to 72 bf16 (144B) rows:
// bank quads become 4*(m+g) mod 32 -> conflict-free b128 reads (stride 128B would be 16-way).
__global__ __launch_bounds__(256) void mlp_kernel(
        const unsigned short* __restrict__ emb, const float* __restrict__ agg,
        unsigned short* __restrict__ emb_out,
        const unsigned short* __restrict__ whT, const unsigned short* __restrict__ wfpT,
        const float* __restrict__ bh, const float* __restrict__ bfp,
        float* __restrict__ f, int N) {
    __shared__ unsigned short sV[BM * 72];
    __shared__ unsigned short sWh[64 * 72];
    __shared__ unsigned short sWfp[128 * 72];
    __shared__ float sBh[64];
    __shared__ float sBfp[128];
    __shared__ float sF[128];

    int tid = threadIdx.x;
    int base = blockIdx.x * BM;

    if (tid < 128) { sF[tid] = 0.f; sBfp[tid] = bfp[tid]; }
    if (tid < 64) sBh[tid] = bh[tid];

#pragma unroll
    for (int it = 0; it < 2; ++it) {  // WhT: 4096 bf16
        int idx = it * 2048 + tid * 8;
        *reinterpret_cast<bf16x8*>(sWh + (idx >> 6) * 72 + (idx & 63)) =
            *reinterpret_cast<const bf16x8*>(whT + idx);
    }
#pragma unroll
    for (int it = 0; it < 4; ++it) {  // WfpT: 8192 bf16
        int idx = it * 2048 + tid * 8;
        *reinterpret_cast<bf16x8*>(sWfp + (idx >> 6) * 72 + (idx & 63)) =
            *reinterpret_cast<const bf16x8*>(wfpT + idx);
    }
#pragma unroll
    for (int it = 0; it < 2; ++it) {  // V = emb + agg (bf16)
        int idx = it * 2048 + tid * 8;
        int nl = idx >> 6, k0 = idx & 63;
        bf16x8 vv;
        if (base + nl < N) {
            bf16x8 ev = *reinterpret_cast<const bf16x8*>(emb + (size_t)base * 64 + idx);
            const float* ap = agg + (size_t)base * 64 + idx;
            f32x4 a0 = *reinterpret_cast<const f32x4*>(ap);
            f32x4 a1 = *reinterpret_cast<const f32x4*>(ap + 4);
            float av[8] = {a0.x, a0.y, a0.z, a0.w, a1.x, a1.y, a1.z, a1.w};
#pragma unroll
            for (int j = 0; j < 8; ++j)
                vv[j] = (short)f2bf(bf2f((unsigned short)ev[j]) + av[j]);
        } else {
#pragma unroll
            for (int j = 0; j < 8; ++j) vv[j] = 0;
        }
        *reinterpret_cast<bf16x8*>(sV + nl * 72 + k0) = vv;
    }
    __syncthreads();

    int lane = tid & 63, w = tid >> 6;
    int m16 = lane & 15, g = lane >> 4;
    int arow = w * 16 + m16;

    // ---- GEMM1: r = relu(V @ Wh + bh), per wave a 16x64 strip ----
    bf16x8 a0 = *reinterpret_cast<const bf16x8*>(sV + arow * 72 + g * 8);
    bf16x8 a1 = *reinterpret_cast<const bf16x8*>(sV + arow * 72 + 32 + g * 8);
    f32x4 acc[4];
#pragma unroll
    for (int c = 0; c < 4; ++c) {
        bf16x8 b0 = *reinterpret_cast<const bf16x8*>(sWh + (c * 16 + m16) * 72 + g * 8);
        bf16x8 b1 = *reinterpret_cast<const bf16x8*>(sWh + (c * 16 + m16) * 72 + 32 + g * 8);
        f32x4 z = {0.f, 0.f, 0.f, 0.f};
        z = __builtin_amdgcn_mfma_f32_16x16x32_bf16(a0, b0, z, 0, 0, 0);
        z = __builtin_amdgcn_mfma_f32_16x16x32_bf16(a1, b1, z, 0, 0, 0);
        acc[c] = z;
    }
    // bias + relu; write r back into sV (own rows only) as bf16
    // C layout: row=(lane>>4)*4+reg, col=c*16+(lane&15)  [m89-verified]
#pragma unroll
    for (int c = 0; c < 4; ++c) {
        float bias = sBh[c * 16 + m16];
#pragma unroll
        for (int reg = 0; reg < 4; ++reg) {
            float rv = fmaxf(acc[c][reg] + bias, 0.f);
            sV[(w * 16 + g * 4 + reg) * 72 + c * 16 + m16] = f2bf(rv);
        }
    }
    __syncthreads();

    // store r -> emb (next round), coalesced bf16x8 from LDS
#pragma unroll
    for (int it = 0; it < 2; ++it) {
        int idx = it * 2048 + tid * 8;
        int nl = idx >> 6;
        if (base + nl < N)
            *reinterpret_cast<bf16x8*>(emb_out + (size_t)base * 64 + idx) =
                *reinterpret_cast<const bf16x8*>(sV + nl * 72 + (idx & 63));
    }

    // ---- GEMM2: z = r @ Wfp + bfp  (16 x 128 per wave) ----
    bf16x8 ra0 = *reinterpret_cast<const bf16x8*>(sV + arow * 72 + g * 8);
    bf16x8 ra1 = *reinterpret_cast<const bf16x8*>(sV + arow * 72 + 32 + g * 8);
    f32x4 z[8];
#pragma unroll
    for (int t = 0; t < 8; ++t) {
        bf16x8 b0 = *reinterpret_cast<const bf16x8*>(sWfp + (t * 16 + m16) * 72 + g * 8);
        bf16x8 b1 = *reinterpret_cast<const bf16x8*>(sWfp + (t * 16 + m16) * 72 + 32 + g * 8);
        f32x4 zz = {0.f, 0.f, 0.f, 0.f};
        zz = __builtin_amdgcn_mfma_f32_16x16x32_bf16(ra0, b0, zz, 0, 0, 0);
        zz = __builtin_amdgcn_mfma_f32_16x16x32_bf16(ra1, b1, zz, 0, 0, 0);
        float bias = sBfp[t * 16 + m16];
#pragma unroll
        for (int reg = 0; reg < 4; ++reg) zz[reg] += bias;
        z[t] = zz;
    }

    // ---- softmax over 128 cols per node-row; rows live in 16-lane groups ----
#pragma unroll
    for (int reg = 0; reg < 4; ++reg) {
        float mx = -1e30f;
#pragma unroll
        for (int t = 0; t < 8; ++t) mx = fmaxf(mx, z[t][reg]);
#pragma unroll
        for (int d = 1; d < 16; d <<= 1) mx = fmaxf(mx, __shfl_xor(mx, d));
        float s = 0.f;
#pragma unroll
        for (int t = 0; t < 8; ++t) {
            float p = __expf(z[t][reg] - mx);
            z[t][reg] = p;
            s += p;
        }
#pragma unroll
        for (int d = 1; d < 16; d <<= 1) s += __shfl_xor(s, d);
        int node = base + w * 16 + g * 4 + reg;
        float inv = (node < N) ? (1.f / s) : 0.f;
#pragma unroll
        for (int t = 0; t < 8; ++t) z[t][reg] *= inv;
    }
    // column sums over this wave's 16 rows -> block accumulator
#pragma unroll
    for (int t = 0; t < 8; ++t) {
        float v = z[t][0] + z[t][1] + z[t][2] + z[t][3];
        v += __shfl_xor(v, 16);
        v += __shfl_xor(v, 32);
        if (g == 0) atomicAdd(&sF[t * 16 + m16], v);
    }
    __syncthreads();
    if (tid < 128) unsafeAtomicAdd(&f[tid], sF[tid]);
}

__global__ void final_kernel(const float* __restrict__ f, const float* __restrict__ Wcl,
                             const float* __restrict__ bcl, float* __restrict__ out) {
    __shared__ float logits[10];
    int c = threadIdx.x;
    if (c < 10) {
        float acc = bcl[c];
        for (int l = 0; l < LFP; l++) acc = fmaf(f[l], Wcl[l * 10 + c], acc);
        logits[c] = acc;
    }
    __syncthreads();
    if (c == 0) {
        float m = -1e30f;
        for (int i = 0; i < 10; i++) m = fmaxf(m, logits[i]);
        float e[10], s = 0.f;
        for (int i = 0; i < 10; i++) { e[i] = __expf(logits[i] - m); s += e[i]; }
        for (int i = 0; i < 10; i++) out[i] = e[i] / s;
    }
}

extern "C" void kernel_launch(void* const* d_in, const int* in_sizes, int n_in,
                              void* d_out, int out_size, void* d_ws, size_t ws_size,
                              hipStream_t stream) {
    const int* feat = (const int*)d_in[0];
    const int* esrc = (const int*)d_in[1];
    const int* edst = (const int*)d_in[2];
    const float* table = (const float*)d_in[3];
    const float* Wh = (const float*)d_in[4];
    const float* bh = (const float*)d_in[5];
    const float* Wfp = (const float*)d_in[6];
    const float* bfp = (const float*)d_in[7];
    const float* Wcl = (const float*)d_in[8];
    const float* bcl = (const float*)d_in[9];
    float* out = (float*)d_out;
    int N = in_sizes[0];
    int nE = in_sizes[1];

    char* ws = (char*)d_ws;
    float* agg = (float*)ws;                                        // N*64*4 B
    float* f = (float*)(ws + (size_t)N * 64 * 4);                   // 512 B
    unsigned short* whT = (unsigned short*)(ws + (size_t)N * 64 * 4 + 512);   // 32 KB
    unsigned short* wfpT = whT + RROUNDS * 64 * 64;                 // 64 KB
    unsigned short* embB = wfpT + RROUNDS * 128 * 64;               // N*64*2 B

    prep_kernel<<<192, 256, 0, stream>>>(Wh, Wfp, whT, wfpT);
    init_kernel<<<(N * FDIM + 255) / 256, 256, 0, stream>>>(feat, table, embB, f, N);

    for (int r = 0; r < RROUNDS; ++r) {
        hipMemsetAsync(agg, 0, (size_t)N * FDIM * sizeof(float), stream);
        long long tot = (long long)nE * FDIM;
        scatter_kernel<<<(int)((tot + 255) / 256), 256, 0, stream>>>(embB, agg, esrc, edst, nE);
        mlp_kernel<<<(N + BM - 1) / BM, 256, 0, stream>>>(
            embB, agg, embB, whT + (size_t)r * 4096, wfpT + (size_t)r * 8192,
            bh + (size_t)r * FDIM, bfp + (size_t)r * LFP, f, N);
    }

    final_kernel<<<1, 64, 0, stream>>>(f, Wcl, bcl, out);
}

// Round 3
// 361.705 us; speedup vs baseline: 8.5221x; 2.3818x over previous
//
#include <hip/hip_runtime.h>
#include <hip/hip_bf16.h>

#define FDIM 64
#define LFP 128
#define RROUNDS 4
#define BM 64      // nodes per block in mlp kernel
#define SCAN_B 1024

typedef __attribute__((ext_vector_type(8))) short bf16x8;
typedef __attribute__((ext_vector_type(4))) float f32x4;

__device__ __forceinline__ float bf2f(unsigned short u) {
    unsigned int x = ((unsigned int)u) << 16;
    float f;
    __builtin_memcpy(&f, &x, 4);
    return f;
}
__device__ __forceinline__ unsigned short f2bf(float x) {
    unsigned int u;
    __builtin_memcpy(&u, &x, 4);
    unsigned int r = (u + 0x7fffu + ((u >> 16) & 1u)) >> 16;  // RNE
    return (unsigned short)r;
}

// ---------------- CSR build ----------------
__global__ void hist_kernel(const int* __restrict__ dst, int* __restrict__ cnt, int nE) {
    int e = blockIdx.x * blockDim.x + threadIdx.x;
    if (e < nE) atomicAdd(&cnt[dst[e]], 1);
}

// block-local exclusive scan over SCAN_B elements (256 thr x 4), writes block total
__global__ __launch_bounds__(256) void scan1_kernel(const int* __restrict__ cnt,
                                                    int* __restrict__ rp, int* __restrict__ bsum, int n) {
    __shared__ int s[256];
    int t = threadIdx.x;
    int base = blockIdx.x * SCAN_B;
    int v[4], sum = 0;
#pragma unroll
    for (int i = 0; i < 4; i++) {
        int idx = base + t * 4 + i;
        v[i] = (idx < n) ? cnt[idx] : 0;
        sum += v[i];
    }
    s[t] = sum;
    __syncthreads();
    for (int d = 1; d < 256; d <<= 1) {
        int x = (t >= d) ? s[t - d] : 0;
        __syncthreads();
        s[t] += x;
        __syncthreads();
    }
    int excl = (t > 0) ? s[t - 1] : 0;
#pragma unroll
    for (int i = 0; i < 4; i++) {
        int idx = base + t * 4 + i;
        if (idx < n) { rp[idx] = excl; excl += v[i]; }
    }
    if (t == 255) bsum[blockIdx.x] = s[255];
}

__global__ void scan2_kernel(int* __restrict__ bsum, int nb) {
    if (threadIdx.x == 0 && blockIdx.x == 0) {
        int acc = 0;
        for (int i = 0; i < nb; i++) { int x = bsum[i]; bsum[i] = acc; acc += x; }
    }
}

__global__ void scan3_kernel(int* __restrict__ rp, const int* __restrict__ bsum,
                             int* __restrict__ cursor, int n, int nE) {
    int idx = blockIdx.x * blockDim.x + threadIdx.x;
    if (idx < n) {
        int v = rp[idx] + bsum[idx / SCAN_B];
        rp[idx] = v;
        cursor[idx] = v;
    }
    if (idx == n) rp[n] = nE;
}

__global__ void fill_kernel(const int* __restrict__ src, const int* __restrict__ dst,
                            int* __restrict__ cursor, int* __restrict__ csr, int nE) {
    int e = blockIdx.x * blockDim.x + threadIdx.x;
    if (e < nE) {
        int p = atomicAdd(&cursor[dst[e]], 1);
        csr[p] = src[e];
    }
}

// ---------------- pipeline ----------------
__global__ void prep_kernel(const float* __restrict__ Wh, const float* __restrict__ Wfp,
                            unsigned short* __restrict__ whT, unsigned short* __restrict__ wfpT) {
    int o = blockIdx.x * blockDim.x + threadIdx.x;
    if (o < RROUNDS * FDIM * FDIM) {
        int r = o >> 12, rem = o & 4095, j = rem >> 6, k = rem & 63;
        whT[o] = f2bf(Wh[r * 4096 + k * 64 + j]);
    } else {
        int o2 = o - RROUNDS * FDIM * FDIM;
        int r = o2 >> 13, rem = o2 & 8191, l = rem >> 6, k = rem & 63;
        wfpT[o2] = f2bf(Wfp[r * 8192 + k * 128 + l]);
    }
}

__global__ void init_kernel(const int* __restrict__ feat, const float* __restrict__ table,
                            unsigned short* __restrict__ emb, float* __restrict__ f, int n) {
    int gid = blockIdx.x * blockDim.x + threadIdx.x;
    if (gid < n * FDIM) {
        int node = gid >> 6;
        int d = gid & 63;
        emb[gid] = f2bf(table[feat[node] * FDIM + d]);
    }
    if (gid < LFP) f[gid] = 0.f;
}

// one wave per node: v[n] = emb[n] + sum_{nbr} emb[nbr], via CSR (no atomics)
// 4 neighbors/iter: 16 lanes x ushort4 (8B) = one full 128B emb row per neighbor
__global__ __launch_bounds__(256) void gather_kernel(
        const unsigned short* __restrict__ emb, const int* __restrict__ rp,
        const int* __restrict__ csr, unsigned short* __restrict__ vbuf, int N) {
    int wid = (int)((blockIdx.x * 256 + threadIdx.x) >> 6);
    int lane = threadIdx.x & 63;
    if (wid >= N) return;
    int start = rp[wid], end = rp[wid + 1];
    int grp = lane >> 4, q = lane & 15;
    float a0 = 0.f, a1 = 0.f, a2 = 0.f, a3 = 0.f;
    for (int j = start; j < end; j += 4) {
        int jj = j + grp;
        if (jj < end) {
            int nb = csr[jj];
            ushort4 u = *reinterpret_cast<const ushort4*>(emb + (size_t)nb * 64 + q * 4);
            a0 += bf2f(u.x); a1 += bf2f(u.y); a2 += bf2f(u.z); a3 += bf2f(u.w);
        }
    }
    // reduce the 4 neighbor-groups (lanes xor 16, 32)
    a0 += __shfl_xor(a0, 16); a0 += __shfl_xor(a0, 32);
    a1 += __shfl_xor(a1, 16); a1 += __shfl_xor(a1, 32);
    a2 += __shfl_xor(a2, 16); a2 += __shfl_xor(a2, 32);
    a3 += __shfl_xor(a3, 16); a3 += __shfl_xor(a3, 32);
    if (grp == 0) {
        ushort4 self = *reinterpret_cast<const ushort4*>(emb + (size_t)wid * 64 + q * 4);
        ushort4 o;
        o.x = f2bf(a0 + bf2f(self.x));
        o.y = f2bf(a1 + bf2f(self.y));
        o.z = f2bf(a2 + bf2f(self.z));
        o.w = f2bf(a3 + bf2f(self.w));
        *reinterpret_cast<ushort4*>(vbuf + (size_t)wid * 64 + q * 4) = o;
    }
}

// MFMA MLP: block = 64 nodes, 4 waves. LDS rows padded to 72 bf16 (144B):
// conflict-free b128 reads (stride 128B would be 16-way).
__global__ __launch_bounds__(256) void mlp_kernel(
        const unsigned short* __restrict__ vbuf, unsigned short* __restrict__ emb_out,
        const unsigned short* __restrict__ whT, const unsigned short* __restrict__ wfpT,
        const float* __restrict__ bh, const float* __restrict__ bfp,
        float* __restrict__ f, int N) {
    __shared__ unsigned short sV[BM * 72];
    __shared__ unsigned short sWh[64 * 72];
    __shared__ unsigned short sWfp[128 * 72];
    __shared__ float sBh[64];
    __shared__ float sBfp[128];
    __shared__ float sF[128];

    int tid = threadIdx.x;
    int base = blockIdx.x * BM;

    if (tid < 128) { sF[tid] = 0.f; sBfp[tid] = bfp[tid]; }
    if (tid < 64) sBh[tid] = bh[tid];

#pragma unroll
    for (int it = 0; it < 2; ++it) {  // WhT: 4096 bf16
        int idx = it * 2048 + tid * 8;
        *reinterpret_cast<bf16x8*>(sWh + (idx >> 6) * 72 + (idx & 63)) =
            *reinterpret_cast<const bf16x8*>(whT + idx);
    }
#pragma unroll
    for (int it = 0; it < 4; ++it) {  // WfpT: 8192 bf16
        int idx = it * 2048 + tid * 8;
        *reinterpret_cast<bf16x8*>(sWfp + (idx >> 6) * 72 + (idx & 63)) =
            *reinterpret_cast<const bf16x8*>(wfpT + idx);
    }
#pragma unroll
    for (int it = 0; it < 2; ++it) {  // V tile
        int idx = it * 2048 + tid * 8;
        int nl = idx >> 6, k0 = idx & 63;
        bf16x8 vv;
        if (base + nl < N) {
            vv = *reinterpret_cast<const bf16x8*>(vbuf + (size_t)base * 64 + idx);
        } else {
#pragma unroll
            for (int j = 0; j < 8; ++j) vv[j] = 0;
        }
        *reinterpret_cast<bf16x8*>(sV + nl * 72 + k0) = vv;
    }
    __syncthreads();

    int lane = tid & 63, w = tid >> 6;
    int m16 = lane & 15, g = lane >> 4;
    int arow = w * 16 + m16;

    // ---- GEMM1: r = relu(V @ Wh + bh), per wave a 16x64 strip ----
    bf16x8 a0 = *reinterpret_cast<const bf16x8*>(sV + arow * 72 + g * 8);
    bf16x8 a1 = *reinterpret_cast<const bf16x8*>(sV + arow * 72 + 32 + g * 8);
    f32x4 acc[4];
#pragma unroll
    for (int c = 0; c < 4; ++c) {
        bf16x8 b0 = *reinterpret_cast<const bf16x8*>(sWh + (c * 16 + m16) * 72 + g * 8);
        bf16x8 b1 = *reinterpret_cast<const bf16x8*>(sWh + (c * 16 + m16) * 72 + 32 + g * 8);
        f32x4 z = {0.f, 0.f, 0.f, 0.f};
        z = __builtin_amdgcn_mfma_f32_16x16x32_bf16(a0, b0, z, 0, 0, 0);
        z = __builtin_amdgcn_mfma_f32_16x16x32_bf16(a1, b1, z, 0, 0, 0);
        acc[c] = z;
    }
    // C layout: row=(lane>>4)*4+reg, col=c*16+(lane&15)
#pragma unroll
    for (int c = 0; c < 4; ++c) {
        float bias = sBh[c * 16 + m16];
#pragma unroll
        for (int reg = 0; reg < 4; ++reg) {
            float rv = fmaxf(acc[c][reg] + bias, 0.f);
            sV[(w * 16 + g * 4 + reg) * 72 + c * 16 + m16] = f2bf(rv);
        }
    }
    __syncthreads();

    // store r -> emb (next round)
#pragma unroll
    for (int it = 0; it < 2; ++it) {
        int idx = it * 2048 + tid * 8;
        int nl = idx >> 6;
        if (base + nl < N)
            *reinterpret_cast<bf16x8*>(emb_out + (size_t)base * 64 + idx) =
                *reinterpret_cast<const bf16x8*>(sV + nl * 72 + (idx & 63));
    }

    // ---- GEMM2: z = r @ Wfp + bfp  (16 x 128 per wave) ----
    bf16x8 ra0 = *reinterpret_cast<const bf16x8*>(sV + arow * 72 + g * 8);
    bf16x8 ra1 = *reinterpret_cast<const bf16x8*>(sV + arow * 72 + 32 + g * 8);
    f32x4 z[8];
#pragma unroll
    for (int t = 0; t < 8; ++t) {
        bf16x8 b0 = *reinterpret_cast<const bf16x8*>(sWfp + (t * 16 + m16) * 72 + g * 8);
        bf16x8 b1 = *reinterpret_cast<const bf16x8*>(sWfp + (t * 16 + m16) * 72 + 32 + g * 8);
        f32x4 zz = {0.f, 0.f, 0.f, 0.f};
        zz = __builtin_amdgcn_mfma_f32_16x16x32_bf16(ra0, b0, zz, 0, 0, 0);
        zz = __builtin_amdgcn_mfma_f32_16x16x32_bf16(ra1, b1, zz, 0, 0, 0);
        float bias = sBfp[t * 16 + m16];
#pragma unroll
        for (int reg = 0; reg < 4; ++reg) zz[reg] += bias;
        z[t] = zz;
    }

    // ---- softmax over 128 cols per node-row (rows live in 16-lane groups) ----
#pragma unroll
    for (int reg = 0; reg < 4; ++reg) {
        float mx = -1e30f;
#pragma unroll
        for (int t = 0; t < 8; ++t) mx = fmaxf(mx, z[t][reg]);
#pragma unroll
        for (int d = 1; d < 16; d <<= 1) mx = fmaxf(mx, __shfl_xor(mx, d));
        float s = 0.f;
#pragma unroll
        for (int t = 0; t < 8; ++t) {
            float p = __expf(z[t][reg] - mx);
            z[t][reg] = p;
            s += p;
        }
#pragma unroll
        for (int d = 1; d < 16; d <<= 1) s += __shfl_xor(s, d);
        int node = base + w * 16 + g * 4 + reg;
        float inv = (node < N) ? (1.f / s) : 0.f;
#pragma unroll
        for (int t = 0; t < 8; ++t) z[t][reg] *= inv;
    }
#pragma unroll
    for (int t = 0; t < 8; ++t) {
        float v = z[t][0] + z[t][1] + z[t][2] + z[t][3];
        v += __shfl_xor(v, 16);
        v += __shfl_xor(v, 32);
        if (g == 0) atomicAdd(&sF[t * 16 + m16], v);
    }
    __syncthreads();
    if (tid < 128) unsafeAtomicAdd(&f[tid], sF[tid]);
}

__global__ void final_kernel(const float* __restrict__ f, const float* __restrict__ Wcl,
                             const float* __restrict__ bcl, float* __restrict__ out) {
    __shared__ float logits[10];
    int c = threadIdx.x;
    if (c < 10) {
        float acc = bcl[c];
        for (int l = 0; l < LFP; l++) acc = fmaf(f[l], Wcl[l * 10 + c], acc);
        logits[c] = acc;
    }
    __syncthreads();
    if (c == 0) {
        float m = -1e30f;
        for (int i = 0; i < 10; i++) m = fmaxf(m, logits[i]);
        float e[10], s = 0.f;
        for (int i = 0; i < 10; i++) { e[i] = __expf(logits[i] - m); s += e[i]; }
        for (int i = 0; i < 10; i++) out[i] = e[i] / s;
    }
}

extern "C" void kernel_launch(void* const* d_in, const int* in_sizes, int n_in,
                              void* d_out, int out_size, void* d_ws, size_t ws_size,
                              hipStream_t stream) {
    const int* feat = (const int*)d_in[0];
    const int* esrc = (const int*)d_in[1];
    const int* edst = (const int*)d_in[2];
    const float* table = (const float*)d_in[3];
    const float* Wh = (const float*)d_in[4];
    const float* bh = (const float*)d_in[5];
    const float* Wfp = (const float*)d_in[6];
    const float* bfp = (const float*)d_in[7];
    const float* Wcl = (const float*)d_in[8];
    const float* bcl = (const float*)d_in[9];
    float* out = (float*)d_out;
    int N = in_sizes[0];
    int nE = in_sizes[1];

    char* ws = (char*)d_ws;
    size_t off = 0;
    auto alloc = [&](size_t bytes) { void* p = ws + off; off += (bytes + 63) & ~(size_t)63; return p; };
    unsigned short* embB = (unsigned short*)alloc((size_t)N * 64 * 2);
    unsigned short* vbuf = (unsigned short*)alloc((size_t)N * 64 * 2);
    float* f           = (float*)alloc(LFP * 4);
    unsigned short* whT  = (unsigned short*)alloc(RROUNDS * 64 * 64 * 2);
    unsigned short* wfpT = (unsigned short*)alloc(RROUNDS * 128 * 64 * 2);
    int* cnt    = (int*)alloc((size_t)N * 4);
    int* rp     = (int*)alloc(((size_t)N + 1) * 4);
    int* cursor = (int*)alloc((size_t)N * 4);
    int* bsum   = (int*)alloc(((size_t)(N + SCAN_B - 1) / SCAN_B) * 4);
    int* csr    = (int*)alloc((size_t)nE * 4);

    int nblk_scan = (N + SCAN_B - 1) / SCAN_B;

    // CSR build (graph static across rounds; rebuilt each call — no cross-call state)
    hipMemsetAsync(cnt, 0, (size_t)N * 4, stream);
    hist_kernel<<<(nE + 255) / 256, 256, 0, stream>>>(edst, cnt, nE);
    scan1_kernel<<<nblk_scan, 256, 0, stream>>>(cnt, rp, bsum, N);
    scan2_kernel<<<1, 64, 0, stream>>>(bsum, nblk_scan);
    scan3_kernel<<<(N + 256) / 256, 256, 0, stream>>>(rp, bsum, cursor, N, nE);
    fill_kernel<<<(nE + 255) / 256, 256, 0, stream>>>(esrc, edst, cursor, csr, nE);

    prep_kernel<<<192, 256, 0, stream>>>(Wh, Wfp, whT, wfpT);
    init_kernel<<<(N * FDIM + 255) / 256, 256, 0, stream>>>(feat, table, embB, f, N);

    for (int r = 0; r < RROUNDS; ++r) {
        gather_kernel<<<(N * 64 + 255) / 256, 256, 0, stream>>>(embB, rp, csr, vbuf, N);
        mlp_kernel<<<(N + BM - 1) / BM, 256, 0, stream>>>(
            vbuf, embB, whT + (size_t)r * 4096, wfpT + (size_t)r * 8192,
            bh + (size_t)r * FDIM, bfp + (size_t)r * LFP, f, N);
    }

    final_kernel<<<1, 64, 0, stream>>>(f, Wcl, bcl, out);
}